// Round 7
// baseline (753.881 us; speedup 1.0000x reference)
//
#include <hip/hip_runtime.h>
#include <stdint.h>

#define B 8192
#define T 512
#define K 24

__device__ __forceinline__ float max3f(float a, float b, float c) {
    return fmaxf(fmaxf(a, b), c);   // fuses to v_max3_f32
}

// Exact first-index argmax over 24 values (tournament; every merge pairs a
// lower-index range vs a higher one, keeping lower on ties via strict >).
__device__ __forceinline__ int argmax24f(const float s[K]) {
    float v[12]; int idx[12];
#pragma unroll
    for (int p = 0; p < 12; ++p) {
        bool gt = s[2*p+1] > s[2*p];
        v[p]   = gt ? s[2*p+1] : s[2*p];
        idx[p] = gt ? 2*p+1 : 2*p;
    }
#pragma unroll
    for (int p = 0; p < 6; ++p) {
        bool gt = v[2*p+1] > v[2*p];
        v[p]   = gt ? v[2*p+1] : v[2*p];
        idx[p] = gt ? idx[2*p+1] : idx[2*p];
    }
#pragma unroll
    for (int p = 0; p < 3; ++p) {
        bool gt = v[2*p+1] > v[2*p];
        v[p]   = gt ? v[2*p+1] : v[2*p];
        idx[p] = gt ? idx[2*p+1] : idx[2*p];
    }
    bool h0 = v[1] > v[0]; float x0 = h0 ? v[1] : v[0]; int y0 = h0 ? idx[1] : idx[0];
    bool h1 = v[2] > x0;
    return h1 ? idx[2] : y0;
}

// ---------------------------------------------------------------------------
// Forward Viterbi, VALUE-ONLY (no backpointers). 64-thread block = one wave =
// 8 batches (8 lanes x 3 cols). Alpha exchange via LDS within the wave
// (in-order DS pipe -> no barriers). Max via v_max3 trees (order-free exact).
// Writes alpha_t (the recurrence state) straight into d_out[b][t][:] — the
// backtrack kernel recomputes exact argmax from it and overwrites with onehot.
// ---------------------------------------------------------------------------
__global__ __launch_bounds__(64) __attribute__((amdgpu_waves_per_eu(1, 1)))
void crf_forward(const float* __restrict__ inp,    // [B, T, K]
                 const float* __restrict__ trans,  // [K, K] (prev i -> cur j)
                 float* __restrict__ out)          // [B, T, K] <- alpha
{
    __shared__ float alpha[2][8][K];

    const int lane = threadIdx.x;          // one wave per block
    const int g    = lane >> 3;            // batch group 0..7
    const int l    = lane & 7;             // lane within group
    const int c0   = 3 * l;                // this lane's columns c0..c0+2
    const int b    = blockIdx.x * 8 + g;   // 1024 blocks * 8 = 8192

    float tc[3][K];                        // 72 regs; waves_per_eu(1,1) budget
#pragma unroll
    for (int j = 0; j < 3; ++j)
#pragma unroll
        for (int i = 0; i < K; ++i) tc[j][i] = trans[i * K + c0 + j];

    const float* ebl = inp + (size_t)b * T * K + c0;
    float*       obl = out + (size_t)b * T * K + c0;

    float* a0 = &alpha[0][g][0];
    float* a1 = &alpha[1][g][0];

    // t = 0: alpha_0 = emissions_0 (also stored to out)
    {
        float x0 = ebl[0], x1 = ebl[1], x2 = ebl[2];
        a0[c0] = x0; a0[c0 + 1] = x1; a0[c0 + 2] = x2;
        obl[0] = x0; obl[1] = x1; obl[2] = x2;
    }
    float e0 = ebl[K],     e1 = ebl[K + 1],     e2 = ebl[K + 2];      // e(1)
    float f0 = ebl[2 * K], f1 = ebl[2 * K + 1], f2 = ebl[2 * K + 2];  // e(2)

// One step: broadcast-read alpha (6 x b128), per column 24 adds + max3 tree
// (12 ops), update LDS alpha + store alpha row slice to global.
#define STEP(AC, AN, E0, E1, E2, TT) do {                                     \
    float a_[K];                                                              \
    _Pragma("unroll")                                                         \
    for (int c = 0; c < 6; ++c) {                                             \
        float4 v_ = ((const float4*)(AC))[c];                                 \
        a_[4*c] = v_.x; a_[4*c+1] = v_.y; a_[4*c+2] = v_.z; a_[4*c+3] = v_.w; \
    }                                                                         \
    float r_[3];                                                              \
    _Pragma("unroll")                                                         \
    for (int j = 0; j < 3; ++j) {                                             \
        float u_[8];                                                          \
        _Pragma("unroll")                                                     \
        for (int k = 0; k < 8; ++k)                                           \
            u_[k] = max3f(a_[3*k]   + tc[j][3*k],                             \
                          a_[3*k+1] + tc[j][3*k+1],                           \
                          a_[3*k+2] + tc[j][3*k+2]);                          \
        float w0_ = max3f(u_[0], u_[1], u_[2]);                               \
        float w1_ = max3f(u_[3], u_[4], u_[5]);                               \
        float w2_ = fmaxf(u_[6], u_[7]);                                      \
        r_[j] = max3f(w0_, w1_, w2_);                                         \
    }                                                                         \
    float o0_ = r_[0] + (E0), o1_ = r_[1] + (E1), o2_ = r_[2] + (E2);         \
    (AN)[c0] = o0_; (AN)[c0+1] = o1_; (AN)[c0+2] = o2_;                       \
    float* gp_ = obl + (size_t)(TT) * K;                                      \
    gp_[0] = o0_; gp_[1] = o1_; gp_[2] = o2_;                                 \
} while (0)

#pragma unroll 1
    for (int it = 0; it < 255; ++it) {
        const int t = 1 + 2 * it;               // 1,3,...,509
        const float* pa = ebl + (size_t)(t + 2) * K;   // e(t+2) always valid
        float g0 = pa[0], g1 = pa[1], g2 = pa[2];
        STEP(a0, a1, e0, e1, e2, t);
        int tb = t + 3; tb = tb > 511 ? 511 : tb;
        const float* pb = ebl + (size_t)tb * K;
        float h0 = pb[0], h1 = pb[1], h2 = pb[2];
        STEP(a1, a0, f0, f1, f2, t + 1);
        e0 = g0; e1 = g1; e2 = g2;
        f0 = h0; f1 = h1; f2 = h2;
    }
    STEP(a0, a1, e0, e1, e2, 511);              // t = 511 (final)
#undef STEP
}

// ---------------------------------------------------------------------------
// Fused backtrack + one-hot. One thread per batch (64 lanes = 64 batches per
// wave, full SIMT efficiency). Walks t = 511..0: reads alpha record (8-deep
// static-slot prefetch ~6 MB in flight chip-wide), recomputes the EXACT
// first-index argmax of alpha_t[i] + trans[i][cur], overwrites the record
// with the one-hot. transT in LDS with stride-25 rows (25 coprime 32 ->
// conflict-free banks).
// ---------------------------------------------------------------------------
__global__ __launch_bounds__(64) __attribute__((amdgpu_waves_per_eu(1, 1)))
void crf_backtrack(const float* __restrict__ trans,  // [K, K]
                   float* __restrict__ out)          // [B, T, K] alpha->onehot
{
    __shared__ float transT[K * 25];   // transT[j*25 + i] = trans[i][j]

    const int tid = threadIdx.x;
#pragma unroll
    for (int r = 0; r < 9; ++r) {
        int idx = tid * 9 + r;         // 0..575
        int i = idx / 24, j = idx - 24 * i;
        transT[j * 25 + i] = trans[idx];
    }
    __syncthreads();

    const int b = blockIdx.x * 64 + tid;   // 128 blocks * 64 = 8192
    float* ob = out + (size_t)b * T * K;

    float4 q[8][6];                        // 192 VGPRs of prefetched records

#define QLOAD(S, TT) do {                                                     \
    if ((TT) >= 0) {                                                          \
        const float4* r_ = (const float4*)(ob + (size_t)(TT) * K);            \
        q[S][0] = r_[0]; q[S][1] = r_[1]; q[S][2] = r_[2];                    \
        q[S][3] = r_[3]; q[S][4] = r_[4]; q[S][5] = r_[5];                    \
    }                                                                         \
} while (0)

#define WRITE_OH(TT, CUR) do {                                                \
    float4* wp_ = (float4*)(ob + (size_t)(TT) * K);                           \
    _Pragma("unroll")                                                         \
    for (int c = 0; c < 6; ++c) {                                             \
        float4 v_;                                                            \
        v_.x = ((CUR) == 4*c+0) ? 1.0f : 0.0f;                                \
        v_.y = ((CUR) == 4*c+1) ? 1.0f : 0.0f;                                \
        v_.z = ((CUR) == 4*c+2) ? 1.0f : 0.0f;                                \
        v_.w = ((CUR) == 4*c+3) ? 1.0f : 0.0f;                                \
        wp_[c] = v_;                                                          \
    }                                                                         \
} while (0)

#define STEP_BT(S, TT) do {                                                   \
    const float* tcp_ = &transT[cur * 25];                                    \
    float s_[K];                                                              \
    _Pragma("unroll")                                                         \
    for (int c = 0; c < 6; ++c) {                                             \
        s_[4*c+0] = q[S][c].x + tcp_[4*c+0];                                  \
        s_[4*c+1] = q[S][c].y + tcp_[4*c+1];                                  \
        s_[4*c+2] = q[S][c].z + tcp_[4*c+2];                                  \
        s_[4*c+3] = q[S][c].w + tcp_[4*c+3];                                  \
    }                                                                         \
    cur = argmax24f(s_);                                                      \
    WRITE_OH(TT, cur);                                                        \
    QLOAD(S, (TT) - 8);                                                       \
} while (0)

    // prologue: recs 511..504 -> slots 7..0  (slot = t & 7)
    QLOAD(7, 511); QLOAD(6, 510); QLOAD(5, 509); QLOAD(4, 508);
    QLOAD(3, 507); QLOAD(2, 506); QLOAD(1, 505); QLOAD(0, 504);

    int cur;
    {   // t = 511: last_tag = first-index argmax of alpha_511
        float s_[K];
#pragma unroll
        for (int c = 0; c < 6; ++c) {
            s_[4*c+0] = q[7][c].x; s_[4*c+1] = q[7][c].y;
            s_[4*c+2] = q[7][c].z; s_[4*c+3] = q[7][c].w;
        }
        cur = argmax24f(s_);
        WRITE_OH(511, cur);
        QLOAD(7, 503);
    }

#pragma unroll 1
    for (int it = 0; it < 63; ++it) {          // t = 510 .. 7
        const int t0 = 510 - 8 * it;
        STEP_BT(6, t0);     STEP_BT(5, t0 - 1);
        STEP_BT(4, t0 - 2); STEP_BT(3, t0 - 3);
        STEP_BT(2, t0 - 4); STEP_BT(1, t0 - 5);
        STEP_BT(0, t0 - 6); STEP_BT(7, t0 - 7);
    }
    // epilogue: t = 6..0
    STEP_BT(6, 6); STEP_BT(5, 5); STEP_BT(4, 4);
    STEP_BT(3, 3); STEP_BT(2, 2); STEP_BT(1, 1); STEP_BT(0, 0);

#undef STEP_BT
#undef WRITE_OH
#undef QLOAD
}

extern "C" void kernel_launch(void* const* d_in, const int* in_sizes, int n_in,
                              void* d_out, int out_size, void* d_ws, size_t ws_size,
                              hipStream_t stream) {
    const float* inp   = (const float*)d_in[0];   // [8192, 512, 24]
    const float* trans = (const float*)d_in[1];   // [24, 24]
    float*       out   = (float*)d_out;           // [8192, 512, 24]

    crf_forward<<<B / 8, 64, 0, stream>>>(inp, trans, out);
    crf_backtrack<<<B / 64, 64, 0, stream>>>(trans, out);
}

// Round 8
// 482.730 us; speedup vs baseline: 1.5617x; 1.5617x over previous
//
#include <hip/hip_runtime.h>
#include <stdint.h>

#define B 8192
#define T 512
#define K 24

__device__ __forceinline__ float max3f(float a, float b, float c) {
    return fmaxf(fmaxf(a, b), c);   // fuses to v_max3_f32
}

// ---------------------------------------------------------------------------
// Forward Viterbi, VALUE-ONLY (no backpointers) — unchanged from round 6.
// 64-thread block = one wave = 8 batches (8 lanes x 3 cols). Alpha exchange
// via LDS within the wave (in-order DS pipe -> no barriers). Max via v_max3
// trees (order-free exact). Writes alpha_t straight into d_out[b][t][:].
// ---------------------------------------------------------------------------
__global__ __launch_bounds__(64) __attribute__((amdgpu_waves_per_eu(1, 1)))
void crf_forward(const float* __restrict__ inp,    // [B, T, K]
                 const float* __restrict__ trans,  // [K, K] (prev i -> cur j)
                 float* __restrict__ out)          // [B, T, K] <- alpha
{
    __shared__ float alpha[2][8][K];

    const int lane = threadIdx.x;          // one wave per block
    const int g    = lane >> 3;            // batch group 0..7
    const int l    = lane & 7;             // lane within group
    const int c0   = 3 * l;                // this lane's columns c0..c0+2
    const int b    = blockIdx.x * 8 + g;   // 1024 blocks * 8 = 8192

    float tc[3][K];                        // 72 regs; waves_per_eu(1,1) budget
#pragma unroll
    for (int j = 0; j < 3; ++j)
#pragma unroll
        for (int i = 0; i < K; ++i) tc[j][i] = trans[i * K + c0 + j];

    const float* ebl = inp + (size_t)b * T * K + c0;
    float*       obl = out + (size_t)b * T * K + c0;

    float* a0 = &alpha[0][g][0];
    float* a1 = &alpha[1][g][0];

    {   // t = 0: alpha_0 = emissions_0 (also stored to out)
        float x0 = ebl[0], x1 = ebl[1], x2 = ebl[2];
        a0[c0] = x0; a0[c0 + 1] = x1; a0[c0 + 2] = x2;
        obl[0] = x0; obl[1] = x1; obl[2] = x2;
    }
    float e0 = ebl[K],     e1 = ebl[K + 1],     e2 = ebl[K + 2];      // e(1)
    float f0 = ebl[2 * K], f1 = ebl[2 * K + 1], f2 = ebl[2 * K + 2];  // e(2)

#define STEP(AC, AN, E0, E1, E2, TT) do {                                     \
    float a_[K];                                                              \
    _Pragma("unroll")                                                         \
    for (int c = 0; c < 6; ++c) {                                             \
        float4 v_ = ((const float4*)(AC))[c];                                 \
        a_[4*c] = v_.x; a_[4*c+1] = v_.y; a_[4*c+2] = v_.z; a_[4*c+3] = v_.w; \
    }                                                                         \
    float r_[3];                                                              \
    _Pragma("unroll")                                                         \
    for (int j = 0; j < 3; ++j) {                                             \
        float u_[8];                                                          \
        _Pragma("unroll")                                                     \
        for (int k = 0; k < 8; ++k)                                           \
            u_[k] = max3f(a_[3*k]   + tc[j][3*k],                             \
                          a_[3*k+1] + tc[j][3*k+1],                           \
                          a_[3*k+2] + tc[j][3*k+2]);                          \
        float w0_ = max3f(u_[0], u_[1], u_[2]);                               \
        float w1_ = max3f(u_[3], u_[4], u_[5]);                               \
        float w2_ = fmaxf(u_[6], u_[7]);                                      \
        r_[j] = max3f(w0_, w1_, w2_);                                         \
    }                                                                         \
    float o0_ = r_[0] + (E0), o1_ = r_[1] + (E1), o2_ = r_[2] + (E2);         \
    (AN)[c0] = o0_; (AN)[c0+1] = o1_; (AN)[c0+2] = o2_;                       \
    float* gp_ = obl + (size_t)(TT) * K;                                      \
    gp_[0] = o0_; gp_[1] = o1_; gp_[2] = o2_;                                 \
} while (0)

#pragma unroll 1
    for (int it = 0; it < 255; ++it) {
        const int t = 1 + 2 * it;               // 1,3,...,509
        const float* pa = ebl + (size_t)(t + 2) * K;   // e(t+2) always valid
        float g0 = pa[0], g1 = pa[1], g2 = pa[2];
        STEP(a0, a1, e0, e1, e2, t);
        int tb = t + 3; tb = tb > 511 ? 511 : tb;
        const float* pb = ebl + (size_t)tb * K;
        float h0 = pb[0], h1 = pb[1], h2 = pb[2];
        STEP(a1, a0, f0, f1, f2, t + 1);
        e0 = g0; e1 = g1; e2 = g2;
        f0 = h0; f1 = h1; f2 = h2;
    }
    STEP(a0, a1, e0, e1, e2, 511);              // t = 511 (final)
#undef STEP
}

// ---------------------------------------------------------------------------
// Wave-wide exact first-index argmax within a 32-lane group.
// Key = (monotonic-uint(s), 255 - i): max key <=> max value, then min index.
// enc equality <=> identical fp32 bits (exact; +0/-0 ambiguity measure-zero).
// ---------------------------------------------------------------------------
__device__ __forceinline__ int group_argmax(float s, int i) {
    int si = __float_as_int(s);
    uint32_t hi = (uint32_t)(si ^ ((si >> 31) | 0x80000000));
    uint32_t lo = (uint32_t)(255 - i);
#pragma unroll
    for (int m = 1; m < 32; m <<= 1) {
        uint32_t ohi = __shfl_xor(hi, m, 32);
        uint32_t olo = __shfl_xor(lo, m, 32);
        bool take = (ohi > hi) || ((ohi == hi) && (olo > lo));
        hi = take ? ohi : hi;
        lo = take ? olo : lo;
    }
    return 255 - (int)lo;
}

// ---------------------------------------------------------------------------
// Fused backtrack + one-hot, 32 lanes per batch (lane i owns tag-row i;
// lanes 24..31 idle-clamped). 2 batches/wave, 256-thr blocks, 1024 blocks
// -> 4096 waves (16/CU). Per step: prefetched alpha_t[i] (8-deep rotation,
// chain-independent addresses) + trans[i][cur] from stride-25 LDS (conflict-
// free) -> butterfly argmax -> coalesced one-hot store.
// ---------------------------------------------------------------------------
__global__ __launch_bounds__(256) void crf_backtrack(
    const float* __restrict__ trans,  // [K, K]
    float* __restrict__ out)          // [B, T, K] alpha -> onehot, in place
{
    __shared__ float tl[K * 25];      // tl[i*25 + j] = trans[i][j]

    const int tid = threadIdx.x;
    for (int idx = tid; idx < K * K; idx += 256) {
        int i = idx / K, j = idx - K * i;
        tl[i * 25 + j] = trans[idx];
    }
    __syncthreads();

    const int lane = tid & 63;
    const int half = lane >> 5;            // batch within wave (0/1)
    const int i    = lane & 31;            // tag row (24..31 idle)
    const int wv   = tid >> 6;
    const int b    = blockIdx.x * 8 + wv * 2 + half;

    const bool act = (i < K);
    const int  io  = act ? i : (K - 1);    // clamped lane offset (in-bounds)

    float* ob = out + (size_t)b * T * K;
    const float* rp = ob + (size_t)511 * K + io;   // prefetch pointer
    float*       wpp = ob + (size_t)511 * K + io;  // write pointer

    float q[8];                            // slot = t & 7
#pragma unroll
    for (int s = 0; s < 8; ++s) { q[7 - s] = *rp; rp -= K; }   // t=511..504

    int cur;
    {   // t = 511: last_tag = first-index argmax of alpha_511
        float s = act ? q[7] : -INFINITY;
        cur = group_argmax(s, i);
        if (act) *wpp = (i == cur) ? 1.0f : 0.0f;
        wpp -= K;
        q[7] = *rp; rp -= K;               // prefetch t=503 into slot 7
    }

#define STEP_BT(S, TT) do {                                                   \
    float tv_ = tl[io * 25 + cur];                                            \
    float s_  = act ? (q[S] + tv_) : -INFINITY;                               \
    cur = group_argmax(s_, i);                                                \
    if (act) *wpp = (i == cur) ? 1.0f : 0.0f;                                 \
    wpp -= K;                                                                 \
    if ((TT) >= 8) { q[S] = *rp; rp -= K; }                                   \
} while (0)

#pragma unroll 1
    for (int it = 0; it < 63; ++it) {      // t = 510 .. 7
        const int t0 = 510 - 8 * it;
        STEP_BT(6, t0);     STEP_BT(5, t0 - 1);
        STEP_BT(4, t0 - 2); STEP_BT(3, t0 - 3);
        STEP_BT(2, t0 - 4); STEP_BT(1, t0 - 5);
        STEP_BT(0, t0 - 6); STEP_BT(7, t0 - 7);
    }
    // epilogue: t = 6..0 (all slots already resident)
    STEP_BT(6, 6); STEP_BT(5, 5); STEP_BT(4, 4);
    STEP_BT(3, 3); STEP_BT(2, 2); STEP_BT(1, 1); STEP_BT(0, 0);
#undef STEP_BT
}

extern "C" void kernel_launch(void* const* d_in, const int* in_sizes, int n_in,
                              void* d_out, int out_size, void* d_ws, size_t ws_size,
                              hipStream_t stream) {
    const float* inp   = (const float*)d_in[0];   // [8192, 512, 24]
    const float* trans = (const float*)d_in[1];   // [24, 24]
    float*       out   = (float*)d_out;           // [8192, 512, 24]

    crf_forward<<<B / 8, 64, 0, stream>>>(inp, trans, out);
    crf_backtrack<<<B / 8, 256, 0, stream>>>(trans, out);
}